// Round 1
// baseline (1289.570 us; speedup 1.0000x reference)
//
#include <hip/hip_runtime.h>
#include <math.h>
#include <stdint.h>

#define NNODES 50000

__device__ __forceinline__ float lrelu(float x){ return x >= 0.f ? x : 0.2f*x; }

// ---- fold resW (3,128,512) and b (3,512) over relations & heads -> (128,128), (128) per layer ----
__global__ void fold_kernel(const float* __restrict__ resW0, const float* __restrict__ b0,
                            const float* __restrict__ resW1, const float* __restrict__ b1,
                            float* __restrict__ resWf, float* __restrict__ biasf)
{
    int gid = blockIdx.x*blockDim.x + threadIdx.x;
    if (gid < 2*128*128){
        int l = gid >> 14;
        int idx = gid & 16383;
        int k = idx >> 7, c = idx & 127;
        const float* rw = l ? resW1 : resW0;
        float s = 0.f;
        for (int r = 0; r < 3; ++r)
            for (int h = 0; h < 4; ++h)
                s += rw[r*65536 + k*512 + h*128 + c];
        resWf[gid] = 0.25f * s;
    }
    if (gid < 256){
        int l = gid >> 7, c = gid & 127;
        const float* bb = l ? b1 : b0;
        float s = 0.f;
        for (int r = 0; r < 3; ++r)
            for (int h = 0; h < 4; ++h)
                s += bb[r*512 + h*128 + c];
        biasf[gid] = 0.25f * s;
    }
}

// ---- CSR build ----
__global__ void hist_kernel(const int* __restrict__ dst, int E, int* __restrict__ cnt)
{
    int e = blockIdx.x*blockDim.x + threadIdx.x;
    if (e < E) atomicAdd(&cnt[dst[e]], 1);
}

__global__ __launch_bounds__(1024) void scan_kernel(const int* __restrict__ cnt_all,
                                                    int* __restrict__ rp_all,
                                                    int* __restrict__ cur_all, int Nn)
{
    int rel = blockIdx.x;
    const int* cnt = cnt_all + (size_t)rel*Nn;
    int* rp  = rp_all  + (size_t)rel*(Nn+1);
    int* cur = cur_all + (size_t)rel*Nn;
    __shared__ int s[1024];
    int tid = threadIdx.x;
    int carry = 0;
    for (int base = 0; base < Nn; base += 1024){
        int i = base + tid;
        int v = (i < Nn) ? cnt[i] : 0;
        s[tid] = v;
        __syncthreads();
        for (int off = 1; off < 1024; off <<= 1){
            int t = (tid >= off) ? s[tid-off] : 0;
            __syncthreads();
            s[tid] += t;
            __syncthreads();
        }
        int incl = s[tid];
        int tot  = s[1023];
        if (i < Nn){ int ex = carry + incl - v; rp[i] = ex; cur[i] = ex; }
        carry += tot;
        __syncthreads();
    }
    if (tid == 0) rp[Nn] = carry;
}

__global__ void scatter_kernel(const int* __restrict__ src, const int* __restrict__ dst,
                               int E, int* __restrict__ cur, int* __restrict__ colb)
{
    int e = blockIdx.x*blockDim.x + threadIdx.x;
    if (e < E){
        int d = dst[e];
        int pos = atomicAdd(&cur[d], 1);
        colb[pos] = src[e];
    }
}

// ---- SGEMM: C(MxNcols) = A(Mx128) @ B(128xNcols)  [+bias] [+relu+bn]  ----
// EPI: 0 = none, 1 = +bias, 2 = +bias, relu, batchnorm(eval)
template<int EPI>
__global__ __launch_bounds__(256) void gemm128(const float* __restrict__ A, const float* __restrict__ B,
    float* __restrict__ C, int M, int Ncols,
    const float* __restrict__ bias, const float* __restrict__ gamma, const float* __restrict__ beta,
    const float* __restrict__ mean, const float* __restrict__ var)
{
    __shared__ float As[32][64];   // [k][m]
    __shared__ float Bs[32][64];   // [k][n]
    const int tid = threadIdx.x;
    const int row0 = blockIdx.y*64, col0 = blockIdx.x*64;
    const int tx = tid & 15, ty = tid >> 4;
    float acc[4][4] = {};
    for (int k0 = 0; k0 < 128; k0 += 32){
        #pragma unroll
        for (int p = 0; p < 2; ++p){
            int idx = tid + p*256;
            int r = idx >> 3, kq = (idx & 7) << 2;
            int gr = row0 + r;
            float4 v = make_float4(0.f,0.f,0.f,0.f);
            if (gr < M) v = *(const float4*)(A + (size_t)gr*128 + k0 + kq);
            As[kq+0][r] = v.x; As[kq+1][r] = v.y; As[kq+2][r] = v.z; As[kq+3][r] = v.w;
        }
        #pragma unroll
        for (int p = 0; p < 2; ++p){
            int idx = tid + p*256;
            int kk = idx >> 4, cq = (idx & 15) << 2;
            *(float4*)&Bs[kk][cq] = *(const float4*)(B + (size_t)(k0+kk)*Ncols + col0 + cq);
        }
        __syncthreads();
        #pragma unroll
        for (int kk = 0; kk < 32; ++kk){
            float4 a4 = *(const float4*)&As[kk][ty<<2];
            float4 b4 = *(const float4*)&Bs[kk][tx<<2];
            float av[4] = {a4.x,a4.y,a4.z,a4.w};
            float bv[4] = {b4.x,b4.y,b4.z,b4.w};
            #pragma unroll
            for (int i = 0; i < 4; ++i)
                #pragma unroll
                for (int j = 0; j < 4; ++j)
                    acc[i][j] = fmaf(av[i], bv[j], acc[i][j]);
        }
        __syncthreads();
    }
    #pragma unroll
    for (int i = 0; i < 4; ++i){
        int r = row0 + (ty<<2) + i;
        if (r >= M) continue;
        int c = col0 + (tx<<2);
        float vv[4] = {acc[i][0], acc[i][1], acc[i][2], acc[i][3]};
        if (EPI >= 1){
            #pragma unroll
            for (int j = 0; j < 4; ++j) vv[j] += bias[c+j];
        }
        if (EPI == 2){
            #pragma unroll
            for (int j = 0; j < 4; ++j){
                int cc = c + j;
                float t = fmaxf(vv[j], 0.f);
                vv[j] = (t - mean[cc]) * rsqrtf(var[cc] + 1e-5f) * gamma[cc] + beta[cc];
            }
        }
        float4 v = make_float4(vv[0],vv[1],vv[2],vv[3]);
        *(float4*)(C + (size_t)r*Ncols + c) = v;
    }
}

// ---- el/er: el[n,h] = sum_c feat[n,h,c]*al[h,c] (one wave per node) ----
__global__ __launch_bounds__(256) void elr_kernel(const float* __restrict__ feat,
    const float* __restrict__ al, const float* __restrict__ ar,
    float* __restrict__ el, float* __restrict__ er, int Nn)
{
    int n = (blockIdx.x*256 + threadIdx.x) >> 6;
    int lane = threadIdx.x & 63;
    if (n >= Nn) return;
    const float4* f = (const float4*)(feat + (size_t)n*512 + lane*8);
    float4 f0 = f[0], f1 = f[1];
    const float4* ap = (const float4*)(al + lane*8);
    const float4* bp = (const float4*)(ar + lane*8);
    float4 a0 = ap[0], a1 = ap[1], r0 = bp[0], r1 = bp[1];
    float sl = f0.x*a0.x + f0.y*a0.y + f0.z*a0.z + f0.w*a0.w
             + f1.x*a1.x + f1.y*a1.y + f1.z*a1.z + f1.w*a1.w;
    float sr = f0.x*r0.x + f0.y*r0.y + f0.z*r0.z + f0.w*r0.w
             + f1.x*r1.x + f1.y*r1.y + f1.z*r1.z + f1.w*r1.w;
    #pragma unroll
    for (int off = 1; off < 16; off <<= 1){
        sl += __shfl_xor(sl, off);
        sr += __shfl_xor(sr, off);
    }
    if ((lane & 15) == 0){
        int h = lane >> 4;
        el[(size_t)n*4 + h] = sl;
        er[(size_t)n*4 + h] = sr;
    }
}

// ---- per-dst aggregation: hm[n,c] += 0.25 * sum_h (sum_e ex*feat[src,h,c]) / (sum_e ex) ----
// one wave per dst node; lane -> head h = lane>>4, channels (lane&15)*8 .. +8 within head
__global__ __launch_bounds__(256) void agg_kernel(const int* __restrict__ rowp, const int* __restrict__ colb,
    const float* __restrict__ el, const float* __restrict__ er, const float* __restrict__ feat,
    float* __restrict__ hm, int Nn)
{
    int n = (blockIdx.x*256 + threadIdx.x) >> 6;
    int lane = threadIdx.x & 63;
    if (n >= Nn) return;
    int beg = rowp[n], end = rowp[n+1];
    if (beg >= end) return;
    float4 ern = *(const float4*)(er + (size_t)n*4);
    // pass 1: per-head max over incoming edges
    float m0=-1e30f, m1=-1e30f, m2=-1e30f, m3=-1e30f;
    for (int base = beg; base < end; base += 64){
        int j = base + lane;
        if (j < end){
            int s = colb[j];
            float4 e4 = *(const float4*)(el + (size_t)s*4);
            m0 = fmaxf(m0, lrelu(e4.x + ern.x));
            m1 = fmaxf(m1, lrelu(e4.y + ern.y));
            m2 = fmaxf(m2, lrelu(e4.z + ern.z));
            m3 = fmaxf(m3, lrelu(e4.w + ern.w));
        }
    }
    #pragma unroll
    for (int off = 1; off < 64; off <<= 1){
        m0 = fmaxf(m0, __shfl_xor(m0, off));
        m1 = fmaxf(m1, __shfl_xor(m1, off));
        m2 = fmaxf(m2, __shfl_xor(m2, off));
        m3 = fmaxf(m3, __shfl_xor(m3, off));
    }
    int h = lane >> 4;
    float a0=0,a1=0,a2=0,a3=0,a4=0,a5=0,a6=0,a7=0;
    float u0=0,u1=0,u2=0,u3=0;
    // pass 2: unnormalized weighted gather + weight sums
    for (int base = beg; base < end; base += 64){
        int j = base + lane;
        int cnt = min(64, end - base);
        float ex0=0,ex1=0,ex2=0,ex3=0; int s = 0;
        if (j < end){
            s = colb[j];
            float4 e4 = *(const float4*)(el + (size_t)s*4);
            ex0 = __expf(lrelu(e4.x + ern.x) - m0);
            ex1 = __expf(lrelu(e4.y + ern.y) - m1);
            ex2 = __expf(lrelu(e4.z + ern.z) - m2);
            ex3 = __expf(lrelu(e4.w + ern.w) - m3);
            u0 += ex0; u1 += ex1; u2 += ex2; u3 += ex3;
        }
        for (int t = 0; t < cnt; ++t){
            int st = __shfl(s, t);
            float w0 = __shfl(ex0, t), w1 = __shfl(ex1, t), w2 = __shfl(ex2, t), w3 = __shfl(ex3, t);
            float w = (h==0) ? w0 : ((h==1) ? w1 : ((h==2) ? w2 : w3));
            const float4* fp = (const float4*)(feat + (size_t)st*512 + lane*8);
            float4 fa = fp[0], fb = fp[1];
            a0 = fmaf(w, fa.x, a0); a1 = fmaf(w, fa.y, a1);
            a2 = fmaf(w, fa.z, a2); a3 = fmaf(w, fa.w, a3);
            a4 = fmaf(w, fb.x, a4); a5 = fmaf(w, fb.y, a5);
            a6 = fmaf(w, fb.z, a6); a7 = fmaf(w, fb.w, a7);
        }
    }
    #pragma unroll
    for (int off = 1; off < 64; off <<= 1){
        u0 += __shfl_xor(u0, off); u1 += __shfl_xor(u1, off);
        u2 += __shfl_xor(u2, off); u3 += __shfl_xor(u3, off);
    }
    float uh = (h==0) ? u0 : ((h==1) ? u1 : ((h==2) ? u2 : u3));
    float sc = 0.25f / uh;
    a0*=sc; a1*=sc; a2*=sc; a3*=sc; a4*=sc; a5*=sc; a6*=sc; a7*=sc;
    // sum across the 4 heads (lanes differing in bits 4..5)
    #pragma unroll
    for (int off = 16; off < 64; off <<= 1){
        a0 += __shfl_xor(a0, off); a1 += __shfl_xor(a1, off);
        a2 += __shfl_xor(a2, off); a3 += __shfl_xor(a3, off);
        a4 += __shfl_xor(a4, off); a5 += __shfl_xor(a5, off);
        a6 += __shfl_xor(a6, off); a7 += __shfl_xor(a7, off);
    }
    if (lane < 16){
        float* o = hm + (size_t)n*128 + lane*8;
        float4 o0 = *(float4*)o;
        float4 o1 = *((float4*)o + 1);
        o0.x += a0; o0.y += a1; o0.z += a2; o0.w += a3;
        o1.x += a4; o1.y += a5; o1.z += a6; o1.w += a7;
        *(float4*)o = o0;
        *((float4*)o + 1) = o1;
    }
}

static inline char* align256(char* p){ return (char*)(((uintptr_t)p + 255) & ~(uintptr_t)255); }

extern "C" void kernel_launch(void* const* d_in, const int* in_sizes, int n_in,
                              void* d_out, int out_size, void* d_ws, size_t ws_size,
                              hipStream_t stream)
{
    const float* x      = (const float*)d_in[0];
    const int* srcs[3]  = {(const int*)d_in[1], (const int*)d_in[3], (const int*)d_in[5]};
    const int* dsts[3]  = {(const int*)d_in[2], (const int*)d_in[4], (const int*)d_in[6]};
    const int  E[3]     = {in_sizes[1], in_sizes[3], in_sizes[5]};
    const float* W0     = (const float*)d_in[7];
    const float* al0    = (const float*)d_in[8];
    const float* ar0    = (const float*)d_in[9];
    const float* resW0  = (const float*)d_in[10];
    const float* b0     = (const float*)d_in[11];
    const float* W1     = (const float*)d_in[12];
    const float* al1    = (const float*)d_in[13];
    const float* ar1    = (const float*)d_in[14];
    const float* resW1  = (const float*)d_in[15];
    const float* b1     = (const float*)d_in[16];
    const float* fcW    = (const float*)d_in[17];
    const float* fcb    = (const float*)d_in[18];
    const float* gamma  = (const float*)d_in[19];
    const float* beta   = (const float*)d_in[20];
    const float* bmean  = (const float*)d_in[21];
    const float* bvar   = (const float*)d_in[22];
    float* out = (float*)d_out;

    // workspace carve
    char* p = (char*)d_ws;
    float* feat  = (float*)p; p += (size_t)NNODES*512*4; p = align256(p);
    float* hm    = (float*)p; p += (size_t)NNODES*128*4; p = align256(p);
    float* h1    = (float*)p; p += (size_t)NNODES*128*4; p = align256(p);
    float* el    = (float*)p; p += (size_t)NNODES*4*4;   p = align256(p);
    float* er    = (float*)p; p += (size_t)NNODES*4*4;   p = align256(p);
    int*   cnt   = (int*)p;   p += (size_t)3*NNODES*4;   p = align256(p);
    int*   rowp  = (int*)p;   p += (size_t)3*(NNODES+1)*4; p = align256(p);
    int*   cur   = (int*)p;   p += (size_t)3*NNODES*4;   p = align256(p);
    int*   colb  = (int*)p;   p += (size_t)(E[0]+E[1]+E[2])*4; p = align256(p);
    float* resWf = (float*)p; p += (size_t)2*128*128*4;  p = align256(p);
    float* biasf = (float*)p; p += (size_t)2*128*4;

    hipMemsetAsync(cnt, 0, (size_t)3*NNODES*sizeof(int), stream);
    fold_kernel<<<(2*128*128 + 255)/256, 256, 0, stream>>>(resW0, b0, resW1, b1, resWf, biasf);
    for (int r = 0; r < 3; ++r)
        hist_kernel<<<(E[r]+255)/256, 256, 0, stream>>>(dsts[r], E[r], cnt + (size_t)r*NNODES);
    scan_kernel<<<3, 1024, 0, stream>>>(cnt, rowp, cur, NNODES);
    int colOff[3] = {0, E[0], E[0]+E[1]};
    for (int r = 0; r < 3; ++r)
        scatter_kernel<<<(E[r]+255)/256, 256, 0, stream>>>(srcs[r], dsts[r], E[r],
                                                           cur + (size_t)r*NNODES, colb + colOff[r]);

    const int MB = (NNODES + 63)/64;
    const int WAVEBLKS = (NNODES + 3)/4;   // one wave per node, 4 waves/block
    dim3 blk(256);

    // ---- layer 0 ----
    gemm128<1><<<dim3(2, MB), blk, 0, stream>>>(x, resWf, hm, NNODES, 128,
                                                biasf, nullptr, nullptr, nullptr, nullptr);
    for (int r = 0; r < 3; ++r){
        gemm128<0><<<dim3(8, MB), blk, 0, stream>>>(x, W0 + (size_t)r*65536, feat, NNODES, 512,
                                                    nullptr, nullptr, nullptr, nullptr, nullptr);
        elr_kernel<<<WAVEBLKS, blk, 0, stream>>>(feat, al0 + (size_t)r*512, ar0 + (size_t)r*512, el, er, NNODES);
        agg_kernel<<<WAVEBLKS, blk, 0, stream>>>(rowp + (size_t)r*(NNODES+1), colb + colOff[r],
                                                 el, er, feat, hm, NNODES);
    }
    gemm128<2><<<dim3(2, MB), blk, 0, stream>>>(hm, fcW, h1, NNODES, 128,
                                                fcb, gamma, beta, bmean, bvar);

    // ---- layer 1 (writes final output) ----
    gemm128<1><<<dim3(2, MB), blk, 0, stream>>>(h1, resWf + 16384, out, NNODES, 128,
                                                biasf + 128, nullptr, nullptr, nullptr, nullptr);
    for (int r = 0; r < 3; ++r){
        gemm128<0><<<dim3(8, MB), blk, 0, stream>>>(h1, W1 + (size_t)r*65536, feat, NNODES, 512,
                                                    nullptr, nullptr, nullptr, nullptr, nullptr);
        elr_kernel<<<WAVEBLKS, blk, 0, stream>>>(feat, al1 + (size_t)r*512, ar1 + (size_t)r*512, el, er, NNODES);
        agg_kernel<<<WAVEBLKS, blk, 0, stream>>>(rowp + (size_t)r*(NNODES+1), colb + colOff[r],
                                                 el, er, feat, out, NNODES);
    }
}

// Round 2
// 801.796 us; speedup vs baseline: 1.6084x; 1.6084x over previous
//
#include <hip/hip_runtime.h>
#include <hip/hip_bf16.h>
#include <math.h>
#include <stdint.h>

#define NNODES 50000

typedef __bf16 bf16x8 __attribute__((ext_vector_type(8)));
typedef float f32x4 __attribute__((ext_vector_type(4)));
typedef unsigned short u16;

__device__ __forceinline__ float lrelu(float x){ return x >= 0.f ? x : 0.2f*x; }
__device__ __forceinline__ float b2f(u16 u){ union{ unsigned int i; float f; } c; c.i = ((unsigned int)u)<<16; return c.f; }
__device__ __forceinline__ u16 f2b(float f){ __hip_bfloat16 h = __float2bfloat16(f); return *(u16*)&h; }

// ---- weight prep: convert + transpose to bf16 [n][k] layouts, fold residual over (r,h) ----
__global__ void prep_kernel(const float* __restrict__ W0, const float* __restrict__ W1,
                            const float* __restrict__ resW0, const float* __restrict__ resW1,
                            const float* __restrict__ b0, const float* __restrict__ b1,
                            const float* __restrict__ fcW,
                            u16* __restrict__ Wtb, u16* __restrict__ resWtb,
                            u16* __restrict__ fcWtb, float* __restrict__ biasf)
{
    int gid = blockIdx.x*blockDim.x + threadIdx.x;
    if (gid < 2*3*512*128){
        int k = gid & 127;
        int n = (gid >> 7) & 511;
        int rl = gid >> 16;
        int r = rl % 3, l = rl / 3;
        const float* W = l ? W1 : W0;
        Wtb[gid] = f2b(W[(size_t)r*65536 + (size_t)k*512 + n]);
    }
    if (gid < 2*128*128){
        int k = gid & 127;
        int n = (gid >> 7) & 127;
        int l = gid >> 14;
        const float* rw = l ? resW1 : resW0;
        float s = 0.f;
        for (int r = 0; r < 3; ++r)
            for (int h = 0; h < 4; ++h)
                s += rw[r*65536 + k*512 + h*128 + n];
        resWtb[gid] = f2b(0.25f*s);
    }
    if (gid < 128*128){
        int k = gid & 127;
        int n = gid >> 7;
        fcWtb[gid] = f2b(fcW[k*128 + n]);
    }
    if (gid < 256){
        int l = gid >> 7, c = gid & 127;
        const float* bb = l ? b1 : b0;
        float s = 0.f;
        for (int r = 0; r < 3; ++r)
            for (int h = 0; h < 4; ++h)
                s += bb[r*512 + h*128 + c];
        biasf[gid] = 0.25f*s;
    }
}

// ---- fp32 -> bf16 bulk convert (n4 = count/4) ----
__global__ void cvt_kernel(const float* __restrict__ in, u16* __restrict__ out, int n4)
{
    int i = blockIdx.x*blockDim.x + threadIdx.x;
    if (i < n4){
        float4 v = ((const float4*)in)[i];
        ushort4 o;
        o.x = f2b(v.x); o.y = f2b(v.y); o.z = f2b(v.z); o.w = f2b(v.w);
        ((ushort4*)out)[i] = o;
    }
}

// ---- CSR build ----
__global__ void hist_kernel(const int* __restrict__ dst, int E, int* __restrict__ cnt)
{
    int e = blockIdx.x*blockDim.x + threadIdx.x;
    if (e < E) atomicAdd(&cnt[dst[e]], 1);
}

__global__ __launch_bounds__(1024) void scan_kernel(const int* __restrict__ cnt_all,
                                                    int* __restrict__ rp_all,
                                                    int* __restrict__ cur_all, int Nn)
{
    int rel = blockIdx.x;
    const int* cnt = cnt_all + (size_t)rel*Nn;
    int* rp  = rp_all  + (size_t)rel*(Nn+1);
    int* cur = cur_all + (size_t)rel*Nn;
    __shared__ int s[1024];
    int tid = threadIdx.x;
    int carry = 0;
    for (int base = 0; base < Nn; base += 1024){
        int i = base + tid;
        int v = (i < Nn) ? cnt[i] : 0;
        s[tid] = v;
        __syncthreads();
        for (int off = 1; off < 1024; off <<= 1){
            int t = (tid >= off) ? s[tid-off] : 0;
            __syncthreads();
            s[tid] += t;
            __syncthreads();
        }
        int incl = s[tid];
        int tot  = s[1023];
        if (i < Nn){ int ex = carry + incl - v; rp[i] = ex; cur[i] = ex; }
        carry += tot;
        __syncthreads();
    }
    if (tid == 0) rp[Nn] = carry;
}

__global__ void scatter_kernel(const int* __restrict__ src, const int* __restrict__ dst,
                               int E, int* __restrict__ cur, int* __restrict__ colb)
{
    int e = blockIdx.x*blockDim.x + threadIdx.x;
    if (e < E){
        int d = dst[e];
        int pos = atomicAdd(&cur[d], 1);
        colb[pos] = src[e];
    }
}

// ---- bf16 MFMA GEMM: C(M x Ncols) = A(M x 128) @ Bt^T, Bt is [n][k] bf16 ----
// EPI 0: write bf16 Cb; EPI 1: +bias -> fp32 Cf; EPI 2: +bias,relu,BN -> bf16 Cb
template<int EPI>
__global__ __launch_bounds__(256) void gemm_bf16(
    const u16* __restrict__ A, const u16* __restrict__ Bt,
    float* __restrict__ Cf, u16* __restrict__ Cb, int M, int Ncols,
    const float* __restrict__ bias, const float* __restrict__ gamma,
    const float* __restrict__ beta, const float* __restrict__ mean,
    const float* __restrict__ var)
{
    __shared__ u16 As[64][136];   // [m][k], +8 pad spreads banks
    __shared__ u16 Bs[64][136];   // [n][k]
    const int tid = threadIdx.x;
    const int row0 = blockIdx.y*64, col0 = blockIdx.x*64;
    {
        int rr = tid >> 4;            // 0..15
        int kk = (tid & 15) * 8;      // bf16 offset, 16B chunks
        #pragma unroll
        for (int i = 0; i < 4; ++i){
            int r = i*16 + rr;
            int gr = row0 + r;
            float4 va = make_float4(0.f,0.f,0.f,0.f);
            if (gr < M) va = *(const float4*)(A + (size_t)gr*128 + kk);
            *(float4*)&As[r][kk] = va;
            float4 vb = *(const float4*)(Bt + (size_t)(col0 + r)*128 + kk);
            *(float4*)&Bs[r][kk] = vb;
        }
    }
    __syncthreads();
    const int lane = tid & 63;
    const int wave = tid >> 6;
    const int wm = (wave >> 1) * 32, wn = (wave & 1) * 32;
    const int r16 = lane & 15, quad = lane >> 4;
    f32x4 acc[2][2] = {};
    #pragma unroll
    for (int ks = 0; ks < 4; ++ks){
        int k = ks*32 + quad*8;
        bf16x8 a0 = *(const bf16x8*)&As[wm + r16][k];
        bf16x8 a1 = *(const bf16x8*)&As[wm + 16 + r16][k];
        bf16x8 b0 = *(const bf16x8*)&Bs[wn + r16][k];
        bf16x8 b1 = *(const bf16x8*)&Bs[wn + 16 + r16][k];
        acc[0][0] = __builtin_amdgcn_mfma_f32_16x16x32_bf16(a0, b0, acc[0][0], 0,0,0);
        acc[0][1] = __builtin_amdgcn_mfma_f32_16x16x32_bf16(a0, b1, acc[0][1], 0,0,0);
        acc[1][0] = __builtin_amdgcn_mfma_f32_16x16x32_bf16(a1, b0, acc[1][0], 0,0,0);
        acc[1][1] = __builtin_amdgcn_mfma_f32_16x16x32_bf16(a1, b1, acc[1][1], 0,0,0);
    }
    #pragma unroll
    for (int i = 0; i < 2; ++i){
        #pragma unroll
        for (int p = 0; p < 4; ++p){
            int row = row0 + wm + i*16 + quad*4 + p;
            if (row >= M) continue;
            #pragma unroll
            for (int j = 0; j < 2; ++j){
                int col = col0 + wn + j*16 + r16;
                float v = acc[i][j][p];
                if (EPI >= 1) v += bias[col];
                if (EPI == 2){
                    float t = fmaxf(v, 0.f);
                    v = (t - mean[col]) * rsqrtf(var[col] + 1e-5f) * gamma[col] + beta[col];
                }
                if (EPI == 1) Cf[(size_t)row*Ncols + col] = v;
                else          Cb[(size_t)row*Ncols + col] = f2b(v);
            }
        }
    }
}

// ---- el/er from bf16 feat: one wave per node ----
__global__ __launch_bounds__(256) void elr_kernel(const u16* __restrict__ featb,
    const float* __restrict__ al, const float* __restrict__ ar,
    float* __restrict__ el, float* __restrict__ er, int Nn)
{
    int n = (blockIdx.x*256 + threadIdx.x) >> 6;
    int lane = threadIdx.x & 63;
    if (n >= Nn) return;
    float4 raw = *(const float4*)(featb + (size_t)n*512 + lane*8);
    const u16* u = (const u16*)&raw;
    float f[8];
    #pragma unroll
    for (int i = 0; i < 8; ++i) f[i] = b2f(u[i]);
    const float4* ap = (const float4*)(al + lane*8);
    const float4* bp = (const float4*)(ar + lane*8);
    float4 a0 = ap[0], a1 = ap[1], r0 = bp[0], r1 = bp[1];
    float sl = f[0]*a0.x + f[1]*a0.y + f[2]*a0.z + f[3]*a0.w
             + f[4]*a1.x + f[5]*a1.y + f[6]*a1.z + f[7]*a1.w;
    float sr = f[0]*r0.x + f[1]*r0.y + f[2]*r0.z + f[3]*r0.w
             + f[4]*r1.x + f[5]*r1.y + f[6]*r1.z + f[7]*r1.w;
    #pragma unroll
    for (int off = 1; off < 16; off <<= 1){
        sl += __shfl_xor(sl, off);
        sr += __shfl_xor(sr, off);
    }
    if ((lane & 15) == 0){
        int h = lane >> 4;
        el[(size_t)n*4 + h] = sl;
        er[(size_t)n*4 + h] = sr;
    }
}

// ---- per-dst aggregation from bf16 feat; adds 0.25*softmax-weighted head-sum into hm ----
__global__ __launch_bounds__(256) void agg_kernel(const int* __restrict__ rowp, const int* __restrict__ colb,
    const float* __restrict__ el, const float* __restrict__ er, const u16* __restrict__ featb,
    float* __restrict__ hm, int Nn)
{
    int n = (blockIdx.x*256 + threadIdx.x) >> 6;
    int lane = threadIdx.x & 63;
    if (n >= Nn) return;
    int beg = rowp[n], end = rowp[n+1];
    if (beg >= end) return;
    float4 ern = *(const float4*)(er + (size_t)n*4);
    float m0=-1e30f, m1=-1e30f, m2=-1e30f, m3=-1e30f;
    for (int base = beg; base < end; base += 64){
        int j = base + lane;
        if (j < end){
            int s = colb[j];
            float4 e4 = *(const float4*)(el + (size_t)s*4);
            m0 = fmaxf(m0, lrelu(e4.x + ern.x));
            m1 = fmaxf(m1, lrelu(e4.y + ern.y));
            m2 = fmaxf(m2, lrelu(e4.z + ern.z));
            m3 = fmaxf(m3, lrelu(e4.w + ern.w));
        }
    }
    #pragma unroll
    for (int off = 1; off < 64; off <<= 1){
        m0 = fmaxf(m0, __shfl_xor(m0, off));
        m1 = fmaxf(m1, __shfl_xor(m1, off));
        m2 = fmaxf(m2, __shfl_xor(m2, off));
        m3 = fmaxf(m3, __shfl_xor(m3, off));
    }
    int h = lane >> 4;
    float a0=0,a1=0,a2=0,a3=0,a4=0,a5=0,a6=0,a7=0;
    float u0=0,u1=0,u2=0,u3=0;
    for (int base = beg; base < end; base += 64){
        int j = base + lane;
        int cnt = min(64, end - base);
        float ex0=0,ex1=0,ex2=0,ex3=0; int s = 0;
        if (j < end){
            s = colb[j];
            float4 e4 = *(const float4*)(el + (size_t)s*4);
            ex0 = __expf(lrelu(e4.x + ern.x) - m0);
            ex1 = __expf(lrelu(e4.y + ern.y) - m1);
            ex2 = __expf(lrelu(e4.z + ern.z) - m2);
            ex3 = __expf(lrelu(e4.w + ern.w) - m3);
            u0 += ex0; u1 += ex1; u2 += ex2; u3 += ex3;
        }
        for (int t = 0; t < cnt; ++t){
            int st = __shfl(s, t);
            float w0 = __shfl(ex0, t), w1 = __shfl(ex1, t), w2 = __shfl(ex2, t), w3 = __shfl(ex3, t);
            float w = (h==0) ? w0 : ((h==1) ? w1 : ((h==2) ? w2 : w3));
            float4 raw = *(const float4*)(featb + (size_t)st*512 + lane*8);
            const u16* uu = (const u16*)&raw;
            a0 = fmaf(w, b2f(uu[0]), a0); a1 = fmaf(w, b2f(uu[1]), a1);
            a2 = fmaf(w, b2f(uu[2]), a2); a3 = fmaf(w, b2f(uu[3]), a3);
            a4 = fmaf(w, b2f(uu[4]), a4); a5 = fmaf(w, b2f(uu[5]), a5);
            a6 = fmaf(w, b2f(uu[6]), a6); a7 = fmaf(w, b2f(uu[7]), a7);
        }
    }
    #pragma unroll
    for (int off = 1; off < 64; off <<= 1){
        u0 += __shfl_xor(u0, off); u1 += __shfl_xor(u1, off);
        u2 += __shfl_xor(u2, off); u3 += __shfl_xor(u3, off);
    }
    float uh = (h==0) ? u0 : ((h==1) ? u1 : ((h==2) ? u2 : u3));
    float sc = 0.25f / uh;
    a0*=sc; a1*=sc; a2*=sc; a3*=sc; a4*=sc; a5*=sc; a6*=sc; a7*=sc;
    #pragma unroll
    for (int off = 16; off < 64; off <<= 1){
        a0 += __shfl_xor(a0, off); a1 += __shfl_xor(a1, off);
        a2 += __shfl_xor(a2, off); a3 += __shfl_xor(a3, off);
        a4 += __shfl_xor(a4, off); a5 += __shfl_xor(a5, off);
        a6 += __shfl_xor(a6, off); a7 += __shfl_xor(a7, off);
    }
    if (lane < 16){
        float* o = hm + (size_t)n*128 + lane*8;
        float4 o0 = *(float4*)o;
        float4 o1 = *((float4*)o + 1);
        o0.x += a0; o0.y += a1; o0.z += a2; o0.w += a3;
        o1.x += a4; o1.y += a5; o1.z += a6; o1.w += a7;
        *(float4*)o = o0;
        *((float4*)o + 1) = o1;
    }
}

static inline char* align256(char* p){ return (char*)(((uintptr_t)p + 255) & ~(uintptr_t)255); }

extern "C" void kernel_launch(void* const* d_in, const int* in_sizes, int n_in,
                              void* d_out, int out_size, void* d_ws, size_t ws_size,
                              hipStream_t stream)
{
    const float* x      = (const float*)d_in[0];
    const int* srcs[3]  = {(const int*)d_in[1], (const int*)d_in[3], (const int*)d_in[5]};
    const int* dsts[3]  = {(const int*)d_in[2], (const int*)d_in[4], (const int*)d_in[6]};
    const int  E[3]     = {in_sizes[1], in_sizes[3], in_sizes[5]};
    const float* W0     = (const float*)d_in[7];
    const float* al0    = (const float*)d_in[8];
    const float* ar0    = (const float*)d_in[9];
    const float* resW0  = (const float*)d_in[10];
    const float* b0     = (const float*)d_in[11];
    const float* W1     = (const float*)d_in[12];
    const float* al1    = (const float*)d_in[13];
    const float* ar1    = (const float*)d_in[14];
    const float* resW1  = (const float*)d_in[15];
    const float* b1     = (const float*)d_in[16];
    const float* fcW    = (const float*)d_in[17];
    const float* fcb    = (const float*)d_in[18];
    const float* gamma  = (const float*)d_in[19];
    const float* beta   = (const float*)d_in[20];
    const float* bmean  = (const float*)d_in[21];
    const float* bvar   = (const float*)d_in[22];
    float* out = (float*)d_out;

    // workspace carve
    char* p = (char*)d_ws;
    u16*   featb = (u16*)p;   p += (size_t)NNODES*512*2; p = align256(p);
    u16*   xbf   = (u16*)p;   p += (size_t)NNODES*128*2; p = align256(p);
    u16*   h1b   = (u16*)p;   p += (size_t)NNODES*128*2; p = align256(p);
    u16*   hmb   = (u16*)p;   p += (size_t)NNODES*128*2; p = align256(p);
    float* hm    = (float*)p; p += (size_t)NNODES*128*4; p = align256(p);
    float* el    = (float*)p; p += (size_t)NNODES*4*4;   p = align256(p);
    float* er    = (float*)p; p += (size_t)NNODES*4*4;   p = align256(p);
    int*   cnt   = (int*)p;   p += (size_t)3*NNODES*4;   p = align256(p);
    int*   rowp  = (int*)p;   p += (size_t)3*(NNODES+1)*4; p = align256(p);
    int*   cur   = (int*)p;   p += (size_t)3*NNODES*4;   p = align256(p);
    int*   colb  = (int*)p;   p += (size_t)(E[0]+E[1]+E[2])*4; p = align256(p);
    u16*   Wtb   = (u16*)p;   p += (size_t)2*3*512*128*2; p = align256(p);
    u16*   resWtb= (u16*)p;   p += (size_t)2*128*128*2;  p = align256(p);
    u16*   fcWtb = (u16*)p;   p += (size_t)128*128*2;    p = align256(p);
    float* biasf = (float*)p; p += (size_t)2*128*4;

    hipMemsetAsync(cnt, 0, (size_t)3*NNODES*sizeof(int), stream);
    prep_kernel<<<(2*3*512*128 + 255)/256, 256, 0, stream>>>(W0, W1, resW0, resW1, b0, b1, fcW,
                                                             Wtb, resWtb, fcWtb, biasf);
    cvt_kernel<<<(NNODES*128/4 + 255)/256, 256, 0, stream>>>(x, xbf, NNODES*128/4);
    for (int r = 0; r < 3; ++r)
        hist_kernel<<<(E[r]+255)/256, 256, 0, stream>>>(dsts[r], E[r], cnt + (size_t)r*NNODES);
    scan_kernel<<<3, 1024, 0, stream>>>(cnt, rowp, cur, NNODES);
    int colOff[3] = {0, E[0], E[0]+E[1]};
    for (int r = 0; r < 3; ++r)
        scatter_kernel<<<(E[r]+255)/256, 256, 0, stream>>>(srcs[r], dsts[r], E[r],
                                                           cur + (size_t)r*NNODES, colb + colOff[r]);

    const int MB = (NNODES + 63)/64;
    const int WAVEBLKS = (NNODES + 3)/4;
    dim3 blk(256);

    // ---- layer 0 ----
    gemm_bf16<1><<<dim3(2, MB), blk, 0, stream>>>(xbf, resWtb, hm, nullptr, NNODES, 128,
                                                  biasf, nullptr, nullptr, nullptr, nullptr);
    for (int r = 0; r < 3; ++r){
        gemm_bf16<0><<<dim3(8, MB), blk, 0, stream>>>(xbf, Wtb + (size_t)r*65536, nullptr, featb,
                                                      NNODES, 512, nullptr, nullptr, nullptr, nullptr, nullptr);
        elr_kernel<<<WAVEBLKS, blk, 0, stream>>>(featb, al0 + (size_t)r*512, ar0 + (size_t)r*512, el, er, NNODES);
        agg_kernel<<<WAVEBLKS, blk, 0, stream>>>(rowp + (size_t)r*(NNODES+1), colb + colOff[r],
                                                 el, er, featb, hm, NNODES);
    }
    cvt_kernel<<<(NNODES*128/4 + 255)/256, 256, 0, stream>>>(hm, hmb, NNODES*128/4);
    gemm_bf16<2><<<dim3(2, MB), blk, 0, stream>>>(hmb, fcWtb, nullptr, h1b, NNODES, 128,
                                                  fcb, gamma, beta, bmean, bvar);

    // ---- layer 1 (writes final output) ----
    gemm_bf16<1><<<dim3(2, MB), blk, 0, stream>>>(h1b, resWtb + 16384, out, nullptr, NNODES, 128,
                                                  biasf + 128, nullptr, nullptr, nullptr, nullptr);
    for (int r = 0; r < 3; ++r){
        gemm_bf16<0><<<dim3(8, MB), blk, 0, stream>>>(h1b, Wtb + (size_t)(3+r)*65536, nullptr, featb,
                                                      NNODES, 512, nullptr, nullptr, nullptr, nullptr, nullptr);
        elr_kernel<<<WAVEBLKS, blk, 0, stream>>>(featb, al1 + (size_t)r*512, ar1 + (size_t)r*512, el, er, NNODES);
        agg_kernel<<<WAVEBLKS, blk, 0, stream>>>(rowp + (size_t)r*(NNODES+1), colb + colOff[r],
                                                 el, er, featb, out, NNODES);
    }
}

// Round 3
// 721.403 us; speedup vs baseline: 1.7876x; 1.1114x over previous
//
#include <hip/hip_runtime.h>
#include <hip/hip_bf16.h>
#include <math.h>
#include <stdint.h>

#define NNODES 50000
#define SCHUNK 4096   // elements per scan block (256 thr × 16)

typedef __bf16 bf16x8 __attribute__((ext_vector_type(8)));
typedef float f32x4 __attribute__((ext_vector_type(4)));
typedef unsigned short u16;

__device__ __forceinline__ float lrelu(float x){ return x >= 0.f ? x : 0.2f*x; }
__device__ __forceinline__ float b2f(u16 u){ union{ unsigned int i; float f; } c; c.i = ((unsigned int)u)<<16; return c.f; }
__device__ __forceinline__ u16 f2b(float f){ __hip_bfloat16 h = __float2bfloat16(f); return *(u16*)&h; }

// ---- weight prep: convert + transpose to bf16 [n][k] layouts, fold residual over (r,h) ----
__global__ void prep_kernel(const float* __restrict__ W0, const float* __restrict__ W1,
                            const float* __restrict__ resW0, const float* __restrict__ resW1,
                            const float* __restrict__ b0, const float* __restrict__ b1,
                            const float* __restrict__ fcW,
                            u16* __restrict__ Wtb, u16* __restrict__ resWtb,
                            u16* __restrict__ fcWtb, float* __restrict__ biasf)
{
    int gid = blockIdx.x*blockDim.x + threadIdx.x;
    if (gid < 2*3*512*128){
        int k = gid & 127;
        int n = (gid >> 7) & 511;
        int rl = gid >> 16;
        int r = rl % 3, l = rl / 3;
        const float* W = l ? W1 : W0;
        Wtb[gid] = f2b(W[(size_t)r*65536 + (size_t)k*512 + n]);
    }
    if (gid < 2*128*128){
        int k = gid & 127;
        int n = (gid >> 7) & 127;
        int l = gid >> 14;
        const float* rw = l ? resW1 : resW0;
        float s = 0.f;
        for (int r = 0; r < 3; ++r)
            for (int h = 0; h < 4; ++h)
                s += rw[r*65536 + k*512 + h*128 + n];
        resWtb[gid] = f2b(0.25f*s);
    }
    if (gid < 128*128){
        int k = gid & 127;
        int n = gid >> 7;
        fcWtb[gid] = f2b(fcW[k*128 + n]);
    }
    if (gid < 256){
        int l = gid >> 7, c = gid & 127;
        const float* bb = l ? b1 : b0;
        float s = 0.f;
        for (int r = 0; r < 3; ++r)
            for (int h = 0; h < 4; ++h)
                s += bb[r*512 + h*128 + c];
        biasf[gid] = 0.25f*s;
    }
}

// ---- fp32 -> bf16 bulk convert (n4 = count/4) ----
__global__ void cvt_kernel(const float* __restrict__ in, u16* __restrict__ out, int n4)
{
    int i = blockIdx.x*blockDim.x + threadIdx.x;
    if (i < n4){
        float4 v = ((const float4*)in)[i];
        ushort4 o;
        o.x = f2b(v.x); o.y = f2b(v.y); o.z = f2b(v.z); o.w = f2b(v.w);
        ((ushort4*)out)[i] = o;
    }
}

// ---- CSR build ----
__global__ void hist_kernel(const int* __restrict__ dst, int E, int* __restrict__ cnt)
{
    int e = blockIdx.x*blockDim.x + threadIdx.x;
    if (e < E) atomicAdd(&cnt[dst[e]], 1);
}

// phase 1: per-chunk sums. grid = (nblk, 3)
__global__ __launch_bounds__(256) void scan_part(const int* __restrict__ cnt_all,
                                                 int* __restrict__ partials, int Nn, int nblk)
{
    int rel = blockIdx.y, blk = blockIdx.x;
    const int* cnt = cnt_all + (size_t)rel*Nn;
    int tid = threadIdx.x;
    int i0 = blk*SCHUNK + tid*16;
    int s = 0;
    #pragma unroll
    for (int k = 0; k < 4; ++k){
        int idx = i0 + k*4;
        if (idx + 3 < Nn){ int4 v = *(const int4*)(cnt + idx); s += v.x+v.y+v.z+v.w; }
        else { for (int j = 0; j < 4; ++j) if (idx+j < Nn) s += cnt[idx+j]; }
    }
    #pragma unroll
    for (int off = 1; off < 64; off <<= 1) s += __shfl_xor(s, off);
    __shared__ int ws[4];
    if ((tid & 63) == 0) ws[tid>>6] = s;
    __syncthreads();
    if (tid == 0) partials[rel*nblk + blk] = ws[0]+ws[1]+ws[2]+ws[3];
}

// phase 2: write exclusive prefix to rp & cur. grid = (nblk, 3)
__global__ __launch_bounds__(256) void scan_write(const int* __restrict__ cnt_all,
                                                  const int* __restrict__ partials,
                                                  int* __restrict__ rp_all, int* __restrict__ cur_all,
                                                  int Nn, int nblk)
{
    int rel = blockIdx.y, blk = blockIdx.x;
    const int* cnt = cnt_all + (size_t)rel*Nn;
    int* rp  = rp_all  + (size_t)rel*(Nn+1);
    int* cur = cur_all + (size_t)rel*Nn;
    int tid = threadIdx.x;
    __shared__ int sOff;
    __shared__ int wsum[4];
    if (tid == 0){
        int o = 0;
        for (int b = 0; b < blk; ++b) o += partials[rel*nblk + b];
        sOff = o;
        if (blk == 0){
            int t = 0;
            for (int b = 0; b < nblk; ++b) t += partials[rel*nblk + b];
            rp[Nn] = t;
        }
    }
    int i0 = blk*SCHUNK + tid*16;
    int v[16];
    int s = 0;
    #pragma unroll
    for (int k = 0; k < 16; ++k){
        int idx = i0 + k;
        v[k] = (idx < Nn) ? cnt[idx] : 0;
        s += v[k];
    }
    int lane = tid & 63;
    int incl = s;
    #pragma unroll
    for (int off = 1; off < 64; off <<= 1){
        int t = __shfl_up(incl, off);
        if (lane >= off) incl += t;
    }
    if (lane == 63) wsum[tid>>6] = incl;
    __syncthreads();
    int woff = 0;
    for (int w = 0; w < (tid>>6); ++w) woff += wsum[w];
    int ex = sOff + woff + incl - s;
    #pragma unroll
    for (int k = 0; k < 16; ++k){
        int idx = i0 + k;
        if (idx < Nn){ rp[idx] = ex; cur[idx] = ex; }
        ex += v[k];
    }
}

__global__ void scatter_kernel(const int* __restrict__ src, const int* __restrict__ dst,
                               int E, int* __restrict__ cur, int* __restrict__ colb)
{
    int e = blockIdx.x*blockDim.x + threadIdx.x;
    if (e < E){
        int d = dst[e];
        int pos = atomicAdd(&cur[d], 1);
        colb[pos] = src[e];
    }
}

// ---- bf16 MFMA GEMM: C(M x Ncols) = A(M x 128) @ Bt^T, Bt is [n][k] bf16 ----
// EPI 0: write bf16 Cb; EPI 1: +bias -> fp32 Cf; EPI 2: +bias,relu,BN -> bf16 Cb
template<int EPI>
__global__ __launch_bounds__(256) void gemm_bf16(
    const u16* __restrict__ A, const u16* __restrict__ Bt,
    float* __restrict__ Cf, u16* __restrict__ Cb, int M, int Ncols,
    const float* __restrict__ bias, const float* __restrict__ gamma,
    const float* __restrict__ beta, const float* __restrict__ mean,
    const float* __restrict__ var)
{
    __shared__ u16 As[64][136];   // [m][k], +8 pad spreads banks
    __shared__ u16 Bs[64][136];   // [n][k]
    const int tid = threadIdx.x;
    const int row0 = blockIdx.y*64, col0 = blockIdx.x*64;
    {
        int rr = tid >> 4;            // 0..15
        int kk = (tid & 15) * 8;      // bf16 offset, 16B chunks
        #pragma unroll
        for (int i = 0; i < 4; ++i){
            int r = i*16 + rr;
            int gr = row0 + r;
            float4 va = make_float4(0.f,0.f,0.f,0.f);
            if (gr < M) va = *(const float4*)(A + (size_t)gr*128 + kk);
            *(float4*)&As[r][kk] = va;
            float4 vb = *(const float4*)(Bt + (size_t)(col0 + r)*128 + kk);
            *(float4*)&Bs[r][kk] = vb;
        }
    }
    __syncthreads();
    const int lane = tid & 63;
    const int wave = tid >> 6;
    const int wm = (wave >> 1) * 32, wn = (wave & 1) * 32;
    const int r16 = lane & 15, quad = lane >> 4;
    f32x4 acc[2][2] = {};
    #pragma unroll
    for (int ks = 0; ks < 4; ++ks){
        int k = ks*32 + quad*8;
        bf16x8 a0 = *(const bf16x8*)&As[wm + r16][k];
        bf16x8 a1 = *(const bf16x8*)&As[wm + 16 + r16][k];
        bf16x8 b0 = *(const bf16x8*)&Bs[wn + r16][k];
        bf16x8 b1 = *(const bf16x8*)&Bs[wn + 16 + r16][k];
        acc[0][0] = __builtin_amdgcn_mfma_f32_16x16x32_bf16(a0, b0, acc[0][0], 0,0,0);
        acc[0][1] = __builtin_amdgcn_mfma_f32_16x16x32_bf16(a0, b1, acc[0][1], 0,0,0);
        acc[1][0] = __builtin_amdgcn_mfma_f32_16x16x32_bf16(a1, b0, acc[1][0], 0,0,0);
        acc[1][1] = __builtin_amdgcn_mfma_f32_16x16x32_bf16(a1, b1, acc[1][1], 0,0,0);
    }
    #pragma unroll
    for (int i = 0; i < 2; ++i){
        #pragma unroll
        for (int p = 0; p < 4; ++p){
            int row = row0 + wm + i*16 + quad*4 + p;
            if (row >= M) continue;
            #pragma unroll
            for (int j = 0; j < 2; ++j){
                int col = col0 + wn + j*16 + r16;
                float v = acc[i][j][p];
                if (EPI >= 1) v += bias[col];
                if (EPI == 2){
                    float t = fmaxf(v, 0.f);
                    v = (t - mean[col]) * rsqrtf(var[col] + 1e-5f) * gamma[col] + beta[col];
                }
                if (EPI == 1) Cf[(size_t)row*Ncols + col] = v;
                else          Cb[(size_t)row*Ncols + col] = f2b(v);
            }
        }
    }
}

// ---- el/er from bf16 feat: one wave per node ----
__global__ __launch_bounds__(256) void elr_kernel(const u16* __restrict__ featb,
    const float* __restrict__ al, const float* __restrict__ ar,
    float* __restrict__ el, float* __restrict__ er, int Nn)
{
    int n = (blockIdx.x*256 + threadIdx.x) >> 6;
    int lane = threadIdx.x & 63;
    if (n >= Nn) return;
    float4 raw = *(const float4*)(featb + (size_t)n*512 + lane*8);
    const u16* u = (const u16*)&raw;
    float f[8];
    #pragma unroll
    for (int i = 0; i < 8; ++i) f[i] = b2f(u[i]);
    const float4* ap = (const float4*)(al + lane*8);
    const float4* bp = (const float4*)(ar + lane*8);
    float4 a0 = ap[0], a1 = ap[1], r0 = bp[0], r1 = bp[1];
    float sl = f[0]*a0.x + f[1]*a0.y + f[2]*a0.z + f[3]*a0.w
             + f[4]*a1.x + f[5]*a1.y + f[6]*a1.z + f[7]*a1.w;
    float sr = f[0]*r0.x + f[1]*r0.y + f[2]*r0.z + f[3]*r0.w
             + f[4]*r1.x + f[5]*r1.y + f[6]*r1.z + f[7]*r1.w;
    #pragma unroll
    for (int off = 1; off < 16; off <<= 1){
        sl += __shfl_xor(sl, off);
        sr += __shfl_xor(sr, off);
    }
    if ((lane & 15) == 0){
        int h = lane >> 4;
        el[(size_t)n*4 + h] = sl;
        er[(size_t)n*4 + h] = sr;
    }
}

// ---- per-dst aggregation from bf16 feat; adds 0.25*softmax-weighted head-sum into hm ----
__global__ __launch_bounds__(256) void agg_kernel(const int* __restrict__ rowp, const int* __restrict__ colb,
    const float* __restrict__ el, const float* __restrict__ er, const u16* __restrict__ featb,
    float* __restrict__ hm, int Nn)
{
    int n = (blockIdx.x*256 + threadIdx.x) >> 6;
    int lane = threadIdx.x & 63;
    if (n >= Nn) return;
    int beg = rowp[n], end = rowp[n+1];
    if (beg >= end) return;
    float4 ern = *(const float4*)(er + (size_t)n*4);
    float m0=-1e30f, m1=-1e30f, m2=-1e30f, m3=-1e30f;
    for (int base = beg; base < end; base += 64){
        int j = base + lane;
        if (j < end){
            int s = colb[j];
            float4 e4 = *(const float4*)(el + (size_t)s*4);
            m0 = fmaxf(m0, lrelu(e4.x + ern.x));
            m1 = fmaxf(m1, lrelu(e4.y + ern.y));
            m2 = fmaxf(m2, lrelu(e4.z + ern.z));
            m3 = fmaxf(m3, lrelu(e4.w + ern.w));
        }
    }
    #pragma unroll
    for (int off = 1; off < 64; off <<= 1){
        m0 = fmaxf(m0, __shfl_xor(m0, off));
        m1 = fmaxf(m1, __shfl_xor(m1, off));
        m2 = fmaxf(m2, __shfl_xor(m2, off));
        m3 = fmaxf(m3, __shfl_xor(m3, off));
    }
    int h = lane >> 4;
    float a0=0,a1=0,a2=0,a3=0,a4=0,a5=0,a6=0,a7=0;
    float u0=0,u1=0,u2=0,u3=0;
    for (int base = beg; base < end; base += 64){
        int j = base + lane;
        int cnt = min(64, end - base);
        float ex0=0,ex1=0,ex2=0,ex3=0; int s = 0;
        if (j < end){
            s = colb[j];
            float4 e4 = *(const float4*)(el + (size_t)s*4);
            ex0 = __expf(lrelu(e4.x + ern.x) - m0);
            ex1 = __expf(lrelu(e4.y + ern.y) - m1);
            ex2 = __expf(lrelu(e4.z + ern.z) - m2);
            ex3 = __expf(lrelu(e4.w + ern.w) - m3);
            u0 += ex0; u1 += ex1; u2 += ex2; u3 += ex3;
        }
        for (int t = 0; t < cnt; ++t){
            int st = __shfl(s, t);
            float w0 = __shfl(ex0, t), w1 = __shfl(ex1, t), w2 = __shfl(ex2, t), w3 = __shfl(ex3, t);
            float w = (h==0) ? w0 : ((h==1) ? w1 : ((h==2) ? w2 : w3));
            float4 raw = *(const float4*)(featb + (size_t)st*512 + lane*8);
            const u16* uu = (const u16*)&raw;
            a0 = fmaf(w, b2f(uu[0]), a0); a1 = fmaf(w, b2f(uu[1]), a1);
            a2 = fmaf(w, b2f(uu[2]), a2); a3 = fmaf(w, b2f(uu[3]), a3);
            a4 = fmaf(w, b2f(uu[4]), a4); a5 = fmaf(w, b2f(uu[5]), a5);
            a6 = fmaf(w, b2f(uu[6]), a6); a7 = fmaf(w, b2f(uu[7]), a7);
        }
    }
    #pragma unroll
    for (int off = 1; off < 64; off <<= 1){
        u0 += __shfl_xor(u0, off); u1 += __shfl_xor(u1, off);
        u2 += __shfl_xor(u2, off); u3 += __shfl_xor(u3, off);
    }
    float uh = (h==0) ? u0 : ((h==1) ? u1 : ((h==2) ? u2 : u3));
    float sc = 0.25f / uh;
    a0*=sc; a1*=sc; a2*=sc; a3*=sc; a4*=sc; a5*=sc; a6*=sc; a7*=sc;
    #pragma unroll
    for (int off = 16; off < 64; off <<= 1){
        a0 += __shfl_xor(a0, off); a1 += __shfl_xor(a1, off);
        a2 += __shfl_xor(a2, off); a3 += __shfl_xor(a3, off);
        a4 += __shfl_xor(a4, off); a5 += __shfl_xor(a5, off);
        a6 += __shfl_xor(a6, off); a7 += __shfl_xor(a7, off);
    }
    if (lane < 16){
        float* o = hm + (size_t)n*128 + lane*8;
        float4 o0 = *(float4*)o;
        float4 o1 = *((float4*)o + 1);
        o0.x += a0; o0.y += a1; o0.z += a2; o0.w += a3;
        o1.x += a4; o1.y += a5; o1.z += a6; o1.w += a7;
        *(float4*)o = o0;
        *((float4*)o + 1) = o1;
    }
}

static inline char* align256(char* p){ return (char*)(((uintptr_t)p + 255) & ~(uintptr_t)255); }

extern "C" void kernel_launch(void* const* d_in, const int* in_sizes, int n_in,
                              void* d_out, int out_size, void* d_ws, size_t ws_size,
                              hipStream_t stream)
{
    const float* x      = (const float*)d_in[0];
    const int* srcs[3]  = {(const int*)d_in[1], (const int*)d_in[3], (const int*)d_in[5]};
    const int* dsts[3]  = {(const int*)d_in[2], (const int*)d_in[4], (const int*)d_in[6]};
    const int  E[3]     = {in_sizes[1], in_sizes[3], in_sizes[5]};
    const float* W0     = (const float*)d_in[7];
    const float* al0    = (const float*)d_in[8];
    const float* ar0    = (const float*)d_in[9];
    const float* resW0  = (const float*)d_in[10];
    const float* b0     = (const float*)d_in[11];
    const float* W1     = (const float*)d_in[12];
    const float* al1    = (const float*)d_in[13];
    const float* ar1    = (const float*)d_in[14];
    const float* resW1  = (const float*)d_in[15];
    const float* b1     = (const float*)d_in[16];
    const float* fcW    = (const float*)d_in[17];
    const float* fcb    = (const float*)d_in[18];
    const float* gamma  = (const float*)d_in[19];
    const float* beta   = (const float*)d_in[20];
    const float* bmean  = (const float*)d_in[21];
    const float* bvar   = (const float*)d_in[22];
    float* out = (float*)d_out;

    // workspace carve
    char* p = (char*)d_ws;
    u16*   featb = (u16*)p;   p += (size_t)NNODES*512*2; p = align256(p);
    u16*   xbf   = (u16*)p;   p += (size_t)NNODES*128*2; p = align256(p);
    u16*   h1b   = (u16*)p;   p += (size_t)NNODES*128*2; p = align256(p);
    u16*   hmb   = (u16*)p;   p += (size_t)NNODES*128*2; p = align256(p);
    float* hm    = (float*)p; p += (size_t)NNODES*128*4; p = align256(p);
    float* el    = (float*)p; p += (size_t)NNODES*4*4;   p = align256(p);
    float* er    = (float*)p; p += (size_t)NNODES*4*4;   p = align256(p);
    int*   cnt   = (int*)p;   p += (size_t)3*NNODES*4;   p = align256(p);
    int*   rowp  = (int*)p;   p += (size_t)3*(NNODES+1)*4; p = align256(p);
    int*   cur   = (int*)p;   p += (size_t)3*NNODES*4;   p = align256(p);
    int*   colb  = (int*)p;   p += (size_t)(E[0]+E[1]+E[2])*4; p = align256(p);
    u16*   Wtb   = (u16*)p;   p += (size_t)2*3*512*128*2; p = align256(p);
    u16*   resWtb= (u16*)p;   p += (size_t)2*128*128*2;  p = align256(p);
    u16*   fcWtb = (u16*)p;   p += (size_t)128*128*2;    p = align256(p);
    float* biasf = (float*)p; p += (size_t)2*128*4;
    int*   parts = (int*)p;   p += (size_t)3*64*4;

    const int NBLK = (NNODES + SCHUNK - 1)/SCHUNK;

    hipMemsetAsync(cnt, 0, (size_t)3*NNODES*sizeof(int), stream);
    prep_kernel<<<(2*3*512*128 + 255)/256, 256, 0, stream>>>(W0, W1, resW0, resW1, b0, b1, fcW,
                                                             Wtb, resWtb, fcWtb, biasf);
    cvt_kernel<<<(NNODES*128/4 + 255)/256, 256, 0, stream>>>(x, xbf, NNODES*128/4);
    for (int r = 0; r < 3; ++r)
        hist_kernel<<<(E[r]+255)/256, 256, 0, stream>>>(dsts[r], E[r], cnt + (size_t)r*NNODES);
    scan_part <<<dim3(NBLK,3), 256, 0, stream>>>(cnt, parts, NNODES, NBLK);
    scan_write<<<dim3(NBLK,3), 256, 0, stream>>>(cnt, parts, rowp, cur, NNODES, NBLK);
    int colOff[3] = {0, E[0], E[0]+E[1]};
    for (int r = 0; r < 3; ++r)
        scatter_kernel<<<(E[r]+255)/256, 256, 0, stream>>>(srcs[r], dsts[r], E[r],
                                                           cur + (size_t)r*NNODES, colb + colOff[r]);

    const int MB = (NNODES + 63)/64;
    const int WAVEBLKS = (NNODES + 3)/4;
    dim3 blk(256);

    // ---- layer 0 ----
    gemm_bf16<1><<<dim3(2, MB), blk, 0, stream>>>(xbf, resWtb, hm, nullptr, NNODES, 128,
                                                  biasf, nullptr, nullptr, nullptr, nullptr);
    for (int r = 0; r < 3; ++r){
        gemm_bf16<0><<<dim3(8, MB), blk, 0, stream>>>(xbf, Wtb + (size_t)r*65536, nullptr, featb,
                                                      NNODES, 512, nullptr, nullptr, nullptr, nullptr, nullptr);
        elr_kernel<<<WAVEBLKS, blk, 0, stream>>>(featb, al0 + (size_t)r*512, ar0 + (size_t)r*512, el, er, NNODES);
        agg_kernel<<<WAVEBLKS, blk, 0, stream>>>(rowp + (size_t)r*(NNODES+1), colb + colOff[r],
                                                 el, er, featb, hm, NNODES);
    }
    cvt_kernel<<<(NNODES*128/4 + 255)/256, 256, 0, stream>>>(hm, hmb, NNODES*128/4);
    gemm_bf16<2><<<dim3(2, MB), blk, 0, stream>>>(hmb, fcWtb, nullptr, h1b, NNODES, 128,
                                                  fcb, gamma, beta, bmean, bvar);

    // ---- layer 1 (writes final output) ----
    gemm_bf16<1><<<dim3(2, MB), blk, 0, stream>>>(h1b, resWtb + 16384, out, nullptr, NNODES, 128,
                                                  biasf + 128, nullptr, nullptr, nullptr, nullptr);
    for (int r = 0; r < 3; ++r){
        gemm_bf16<0><<<dim3(8, MB), blk, 0, stream>>>(h1b, Wtb + (size_t)(3+r)*65536, nullptr, featb,
                                                      NNODES, 512, nullptr, nullptr, nullptr, nullptr, nullptr);
        elr_kernel<<<WAVEBLKS, blk, 0, stream>>>(featb, al1 + (size_t)r*512, ar1 + (size_t)r*512, el, er, NNODES);
        agg_kernel<<<WAVEBLKS, blk, 0, stream>>>(rowp + (size_t)r*(NNODES+1), colb + colOff[r],
                                                 el, er, featb, out, NNODES);
    }
}

// Round 4
// 524.988 us; speedup vs baseline: 2.4564x; 1.3741x over previous
//
#include <hip/hip_runtime.h>
#include <hip/hip_bf16.h>
#include <math.h>
#include <stdint.h>

#define NNODES 50000
#define SCHUNK 4096
#define AW 1664          // A row width: 3*512 aggx + 128 x
#define XOFF 1536        // x-slice offset within A row

typedef __bf16 bf16x8 __attribute__((ext_vector_type(8)));
typedef float f32x4 __attribute__((ext_vector_type(4)));
typedef unsigned short u16;

__device__ __forceinline__ float lrelu(float x){ return x >= 0.f ? x : 0.2f*x; }
__device__ __forceinline__ float b2f(u16 u){ union{ unsigned int i; float f; } c; c.i = ((unsigned int)u)<<16; return c.f; }
__device__ __forceinline__ u16 f2b(float f){ __hip_bfloat16 h = __float2bfloat16(f); return *(u16*)&h; }

// ---- prep: stacked B (1664 x 128) per layer, bias fold ----
// Btb[l][c][j]: j<1536 -> 0.25*W_l[r][k][h*128+c] (j=r*512+h*128+k); j>=1536 -> 0.25*sum_{r,h} resW_l[k][h*128+c]
__global__ void prep_b(const float* __restrict__ W0, const float* __restrict__ W1,
                       const float* __restrict__ resW0, const float* __restrict__ resW1,
                       const float* __restrict__ b0, const float* __restrict__ b1,
                       u16* __restrict__ Btb, float* __restrict__ biasf)
{
    int gid = blockIdx.x*blockDim.x + threadIdx.x;
    if (gid < 2*128*AW){
        int l = gid / (128*AW);
        int rem = gid - l*(128*AW);
        int c = rem / AW;
        int j = rem - c*AW;
        const float* W  = l ? W1 : W0;
        const float* rw = l ? resW1 : resW0;
        float v;
        if (j < XOFF){
            int r = j >> 9, h = (j >> 7) & 3, k = j & 127;
            v = 0.25f * W[(size_t)r*65536 + (size_t)k*512 + h*128 + c];
        } else {
            int k = j - XOFF;
            float s = 0.f;
            for (int r = 0; r < 3; ++r)
                for (int h = 0; h < 4; ++h)
                    s += rw[(size_t)r*65536 + (size_t)k*512 + h*128 + c];
            v = 0.25f * s;
        }
        Btb[gid] = f2b(v);
    }
    if (gid < 256){
        int l = gid >> 7, c = gid & 127;
        const float* bb = l ? b1 : b0;
        float s = 0.f;
        for (int r = 0; r < 3; ++r)
            for (int h = 0; h < 4; ++h)
                s += bb[r*512 + h*128 + c];
        biasf[gid] = 0.25f*s;
    }
}

// ---- prep: wl (128 cols x 128 k) per layer (cols 0..23 = r*8 + lr*4 + h), fcW transpose ----
__global__ void prep_wl(const float* __restrict__ W0, const float* __restrict__ W1,
                        const float* __restrict__ al0, const float* __restrict__ ar0,
                        const float* __restrict__ al1, const float* __restrict__ ar1,
                        const float* __restrict__ fcW,
                        u16* __restrict__ wlb, u16* __restrict__ fcWtb)
{
    int gid = blockIdx.x*blockDim.x + threadIdx.x;
    if (gid < 2*128*128){
        int l = gid >> 14;
        int col = (gid >> 7) & 127;
        int k = gid & 127;
        float v = 0.f;
        if (col < 24){
            int r = col >> 3, lr = (col >> 2) & 1, h = col & 3;
            const float* W = l ? W1 : W0;
            const float* av = l ? (lr ? ar1 : al1) : (lr ? ar0 : al0);
            const float* wrow = W + (size_t)r*65536 + (size_t)k*512 + h*128;
            const float* arow = av + r*512 + h*128;
            for (int cc = 0; cc < 128; ++cc) v += wrow[cc]*arow[cc];
        }
        wlb[gid] = f2b(v);
    }
    if (gid < 128*128){
        int k = gid & 127, n = gid >> 7;
        fcWtb[gid] = f2b(fcW[k*128 + n]);
    }
}

// ---- x fp32 -> bf16 into A x-slice (stride AW) ----
__global__ void cvt_strided(const float* __restrict__ in, u16* __restrict__ Abuf, int Nn)
{
    int gid = blockIdx.x*blockDim.x + threadIdx.x;
    if (gid >= Nn*32) return;
    int n = gid >> 5, q = gid & 31;
    float4 v = *(const float4*)(in + (size_t)n*128 + q*4);
    ushort4 o;
    o.x = f2b(v.x); o.y = f2b(v.y); o.z = f2b(v.z); o.w = f2b(v.w);
    *(ushort4*)(Abuf + (size_t)n*AW + XOFF + q*4) = o;
}

// ---- CSR build ----
__global__ void hist_kernel(const int* __restrict__ dst, int E, int* __restrict__ cnt)
{
    int e = blockIdx.x*blockDim.x + threadIdx.x;
    if (e < E) atomicAdd(&cnt[dst[e]], 1);
}

__global__ __launch_bounds__(256) void scan_part(const int* __restrict__ cnt_all,
                                                 int* __restrict__ partials, int Nn, int nblk)
{
    int rel = blockIdx.y, blk = blockIdx.x;
    const int* cnt = cnt_all + (size_t)rel*Nn;
    int tid = threadIdx.x;
    int i0 = blk*SCHUNK + tid*16;
    int s = 0;
    #pragma unroll
    for (int k = 0; k < 4; ++k){
        int idx = i0 + k*4;
        if (idx + 3 < Nn){ int4 v = *(const int4*)(cnt + idx); s += v.x+v.y+v.z+v.w; }
        else { for (int j = 0; j < 4; ++j) if (idx+j < Nn) s += cnt[idx+j]; }
    }
    #pragma unroll
    for (int off = 1; off < 64; off <<= 1) s += __shfl_xor(s, off);
    __shared__ int ws[4];
    if ((tid & 63) == 0) ws[tid>>6] = s;
    __syncthreads();
    if (tid == 0) partials[rel*nblk + blk] = ws[0]+ws[1]+ws[2]+ws[3];
}

__global__ __launch_bounds__(256) void scan_write(const int* __restrict__ cnt_all,
                                                  const int* __restrict__ partials,
                                                  int* __restrict__ rp_all, int* __restrict__ cur_all,
                                                  int Nn, int nblk)
{
    int rel = blockIdx.y, blk = blockIdx.x;
    const int* cnt = cnt_all + (size_t)rel*Nn;
    int* rp  = rp_all  + (size_t)rel*(Nn+1);
    int* cur = cur_all + (size_t)rel*Nn;
    int tid = threadIdx.x;
    __shared__ int sOff;
    __shared__ int wsum[4];
    if (tid == 0){
        int o = 0;
        for (int b = 0; b < blk; ++b) o += partials[rel*nblk + b];
        sOff = o;
        if (blk == 0){
            int t = 0;
            for (int b = 0; b < nblk; ++b) t += partials[rel*nblk + b];
            rp[Nn] = t;
        }
    }
    int i0 = blk*SCHUNK + tid*16;
    int v[16];
    int s = 0;
    #pragma unroll
    for (int k = 0; k < 16; ++k){
        int idx = i0 + k;
        v[k] = (idx < Nn) ? cnt[idx] : 0;
        s += v[k];
    }
    int lane = tid & 63;
    int incl = s;
    #pragma unroll
    for (int off = 1; off < 64; off <<= 1){
        int t = __shfl_up(incl, off);
        if (lane >= off) incl += t;
    }
    if (lane == 63) wsum[tid>>6] = incl;
    __syncthreads();
    int woff = 0;
    for (int w = 0; w < (tid>>6); ++w) woff += wsum[w];
    int ex = sOff + woff + incl - s;
    #pragma unroll
    for (int k = 0; k < 16; ++k){
        int idx = i0 + k;
        if (idx < Nn){ rp[idx] = ex; cur[idx] = ex; }
        ex += v[k];
    }
}

__global__ void scatter_kernel(const int* __restrict__ src, const int* __restrict__ dst,
                               int E, int* __restrict__ cur, int* __restrict__ colb)
{
    int e = blockIdx.x*blockDim.x + threadIdx.x;
    if (e < E){
        int d = dst[e];
        int pos = atomicAdd(&cur[d], 1);
        colb[pos] = src[e];
    }
}

// ---- bf16 MFMA GEMM, 64x128 block tile, runtime Astride/K/Cstride ----
// EPI 1: +bias -> fp32; EPI 2: +bias,relu,BN -> bf16; EPI 3: raw fp32 (col<ncolsOut guard); EPI 4: +bias -> bf16
// LDS layout: chunk kc of row stored at elem ((kc ^ (row&7))<<3)  (XOR swizzle, 16B aligned)
template<int EPI>
__global__ __launch_bounds__(256) void gemm_k(
    const u16* __restrict__ A, int Astride, int K,
    const u16* __restrict__ Bt,      // [col][K]
    float* __restrict__ Cf, u16* __restrict__ Cb, int Cstride, int ncolsOut,
    int M, const float* __restrict__ bias,
    const float* __restrict__ gamma, const float* __restrict__ beta,
    const float* __restrict__ mean, const float* __restrict__ var)
{
    __shared__ u16 As[64][64];
    __shared__ u16 Bs[128][64];
    const int tid = threadIdx.x;
    const int row0 = blockIdx.y*64, col0 = blockIdx.x*128;
    const int lane = tid & 63;
    const int wave = tid >> 6;
    const int wm = (wave >> 1)*32, wn = (wave & 1)*64;
    const int r16 = lane & 15, quad = lane >> 4;
    const int swzbase = r16 & 7;
    f32x4 acc[2][4] = {};

    for (int k0 = 0; k0 < K; k0 += 64){
        // stage A: 512 chunks of 8 bf16
        #pragma unroll
        for (int p = 0; p < 2; ++p){
            int ch = tid + p*256;
            int r = ch >> 3, kc = ch & 7;
            int gr = row0 + r;
            float4 v = make_float4(0.f,0.f,0.f,0.f);
            if (gr < M) v = *(const float4*)(A + (size_t)gr*Astride + k0 + kc*8);
            *(float4*)&As[r][(kc ^ (r & 7)) << 3] = v;
        }
        // stage B: 1024 chunks
        #pragma unroll
        for (int p = 0; p < 4; ++p){
            int ch = tid + p*256;
            int r = ch >> 3, kc = ch & 7;
            float4 v = *(const float4*)(Bt + (size_t)(col0 + r)*K + k0 + kc*8);
            *(float4*)&Bs[r][(kc ^ (r & 7)) << 3] = v;
        }
        __syncthreads();
        #pragma unroll
        for (int ks = 0; ks < 2; ++ks){
            int swz = ((ks*4 + quad) ^ swzbase) << 3;
            bf16x8 a0 = *(const bf16x8*)&As[wm + r16][swz];
            bf16x8 a1 = *(const bf16x8*)&As[wm + 16 + r16][swz];
            #pragma unroll
            for (int j = 0; j < 4; ++j){
                bf16x8 b = *(const bf16x8*)&Bs[wn + j*16 + r16][swz];
                acc[0][j] = __builtin_amdgcn_mfma_f32_16x16x32_bf16(a0, b, acc[0][j], 0,0,0);
                acc[1][j] = __builtin_amdgcn_mfma_f32_16x16x32_bf16(a1, b, acc[1][j], 0,0,0);
            }
        }
        __syncthreads();
    }
    #pragma unroll
    for (int i = 0; i < 2; ++i){
        #pragma unroll
        for (int p = 0; p < 4; ++p){
            int row = row0 + wm + i*16 + quad*4 + p;
            if (row >= M) continue;
            #pragma unroll
            for (int j = 0; j < 4; ++j){
                int col = col0 + wn + j*16 + r16;
                float v = acc[i][j][p];
                if (EPI == 3){
                    if (col < ncolsOut) Cf[(size_t)row*Cstride + col] = v;
                    continue;
                }
                v += bias[col];
                if (EPI == 2){
                    float t = fmaxf(v, 0.f);
                    v = (t - mean[col]) * rsqrtf(var[col] + 1e-5f) * gamma[col] + beta[col];
                }
                if (EPI == 1) Cf[(size_t)row*Cstride + col] = v;
                else          Cb[(size_t)row*Cstride + col] = f2b(v);
            }
        }
    }
}

// ---- per-dst aggregation of x[src] weighted by per-head softmax ----
// one wave per dst node; lane covers channels 2*lane, 2*lane+1 for all 4 heads
// el_all stride 32: cols roff+0..3 = el heads, roff+4..7 = er heads
__global__ __launch_bounds__(256) void agg_kernel(const int* __restrict__ rowp, const int* __restrict__ colb,
    const float* __restrict__ el_all, int roff,
    const u16* __restrict__ Ax,      // gather source rows (stride AW)
    u16* __restrict__ Aout,          // output slice base (stride AW), writes h*128 + c
    int Nn)
{
    int n = (blockIdx.x*256 + threadIdx.x) >> 6;
    int lane = threadIdx.x & 63;
    if (n >= Nn) return;
    int beg = rowp[n], end = rowp[n+1];
    u16* op = Aout + (size_t)n*AW + lane*2;
    if (beg >= end){
        ushort2 z; z.x = 0; z.y = 0;
        #pragma unroll
        for (int h = 0; h < 4; ++h) *(ushort2*)(op + h*128) = z;
        return;
    }
    float4 ern = *(const float4*)(el_all + (size_t)n*32 + roff + 4);
    float m0=-1e30f, m1=-1e30f, m2=-1e30f, m3=-1e30f;
    for (int base = beg; base < end; base += 64){
        int j = base + lane;
        if (j < end){
            int s = colb[j];
            float4 e4 = *(const float4*)(el_all + (size_t)s*32 + roff);
            m0 = fmaxf(m0, lrelu(e4.x + ern.x));
            m1 = fmaxf(m1, lrelu(e4.y + ern.y));
            m2 = fmaxf(m2, lrelu(e4.z + ern.z));
            m3 = fmaxf(m3, lrelu(e4.w + ern.w));
        }
    }
    #pragma unroll
    for (int off = 1; off < 64; off <<= 1){
        m0 = fmaxf(m0, __shfl_xor(m0, off));
        m1 = fmaxf(m1, __shfl_xor(m1, off));
        m2 = fmaxf(m2, __shfl_xor(m2, off));
        m3 = fmaxf(m3, __shfl_xor(m3, off));
    }
    float acc[4][2] = {};
    float u0=0, u1=0, u2=0, u3=0;
    for (int base = beg; base < end; base += 64){
        int j = base + lane;
        int cnt = min(64, end - base);
        float ex0=0, ex1=0, ex2=0, ex3=0; int s = 0;
        if (j < end){
            s = colb[j];
            float4 e4 = *(const float4*)(el_all + (size_t)s*32 + roff);
            ex0 = __expf(lrelu(e4.x + ern.x) - m0);
            ex1 = __expf(lrelu(e4.y + ern.y) - m1);
            ex2 = __expf(lrelu(e4.z + ern.z) - m2);
            ex3 = __expf(lrelu(e4.w + ern.w) - m3);
            u0 += ex0; u1 += ex1; u2 += ex2; u3 += ex3;
        }
        for (int t = 0; t < cnt; ++t){
            int st = __shfl(s, t);
            float w0 = __shfl(ex0, t), w1 = __shfl(ex1, t);
            float w2 = __shfl(ex2, t), w3 = __shfl(ex3, t);
            ushort2 xv = *(const ushort2*)(Ax + (size_t)st*AW + lane*2);
            float xc0 = b2f(xv.x), xc1 = b2f(xv.y);
            acc[0][0] = fmaf(w0, xc0, acc[0][0]); acc[0][1] = fmaf(w0, xc1, acc[0][1]);
            acc[1][0] = fmaf(w1, xc0, acc[1][0]); acc[1][1] = fmaf(w1, xc1, acc[1][1]);
            acc[2][0] = fmaf(w2, xc0, acc[2][0]); acc[2][1] = fmaf(w2, xc1, acc[2][1]);
            acc[3][0] = fmaf(w3, xc0, acc[3][0]); acc[3][1] = fmaf(w3, xc1, acc[3][1]);
        }
    }
    #pragma unroll
    for (int off = 1; off < 64; off <<= 1){
        u0 += __shfl_xor(u0, off); u1 += __shfl_xor(u1, off);
        u2 += __shfl_xor(u2, off); u3 += __shfl_xor(u3, off);
    }
    float sc[4] = {1.f/u0, 1.f/u1, 1.f/u2, 1.f/u3};
    #pragma unroll
    for (int h = 0; h < 4; ++h){
        ushort2 o;
        o.x = f2b(acc[h][0]*sc[h]);
        o.y = f2b(acc[h][1]*sc[h]);
        *(ushort2*)(op + h*128) = o;
    }
}

static inline char* align256(char* p){ return (char*)(((uintptr_t)p + 255) & ~(uintptr_t)255); }

extern "C" void kernel_launch(void* const* d_in, const int* in_sizes, int n_in,
                              void* d_out, int out_size, void* d_ws, size_t ws_size,
                              hipStream_t stream)
{
    const float* x      = (const float*)d_in[0];
    const int* srcs[3]  = {(const int*)d_in[1], (const int*)d_in[3], (const int*)d_in[5]};
    const int* dsts[3]  = {(const int*)d_in[2], (const int*)d_in[4], (const int*)d_in[6]};
    const int  E[3]     = {in_sizes[1], in_sizes[3], in_sizes[5]};
    const float* W0     = (const float*)d_in[7];
    const float* al0    = (const float*)d_in[8];
    const float* ar0    = (const float*)d_in[9];
    const float* resW0  = (const float*)d_in[10];
    const float* b0     = (const float*)d_in[11];
    const float* W1     = (const float*)d_in[12];
    const float* al1    = (const float*)d_in[13];
    const float* ar1    = (const float*)d_in[14];
    const float* resW1  = (const float*)d_in[15];
    const float* b1     = (const float*)d_in[16];
    const float* fcW    = (const float*)d_in[17];
    const float* fcb    = (const float*)d_in[18];
    const float* gamma  = (const float*)d_in[19];
    const float* beta   = (const float*)d_in[20];
    const float* bmean  = (const float*)d_in[21];
    const float* bvar   = (const float*)d_in[22];
    float* out = (float*)d_out;

    // workspace carve  (~190 MB)
    char* p = (char*)d_ws;
    u16*   Abuf  = (u16*)p;   p += (size_t)NNODES*AW*2;    p = align256(p);
    float* el    = (float*)p; p += (size_t)NNODES*32*4;    p = align256(p);
    u16*   hmb   = (u16*)p;   p += (size_t)NNODES*128*2;   p = align256(p);
    int*   cnt   = (int*)p;   p += (size_t)3*NNODES*4;     p = align256(p);
    int*   rowp  = (int*)p;   p += (size_t)3*(NNODES+1)*4; p = align256(p);
    int*   cur   = (int*)p;   p += (size_t)3*NNODES*4;     p = align256(p);
    int*   colb  = (int*)p;   p += (size_t)(E[0]+E[1]+E[2])*4; p = align256(p);
    u16*   Btb   = (u16*)p;   p += (size_t)2*128*AW*2;     p = align256(p);
    u16*   wlb   = (u16*)p;   p += (size_t)2*128*128*2;    p = align256(p);
    u16*   fcWtb = (u16*)p;   p += (size_t)128*128*2;      p = align256(p);
    float* biasf = (float*)p; p += (size_t)2*128*4;        p = align256(p);
    int*   parts = (int*)p;   p += (size_t)3*64*4;

    const int NBLK = (NNODES + SCHUNK - 1)/SCHUNK;
    const int MB = (NNODES + 63)/64;
    const int WAVEBLKS = (NNODES + 3)/4;
    dim3 blk(256);
    u16* Ax = Abuf + XOFF;

    hipMemsetAsync(cnt, 0, (size_t)3*NNODES*sizeof(int), stream);
    prep_b <<<(2*128*AW + 255)/256, blk, 0, stream>>>(W0, W1, resW0, resW1, b0, b1, Btb, biasf);
    prep_wl<<<(2*128*128 + 255)/256, blk, 0, stream>>>(W0, W1, al0, ar0, al1, ar1, fcW, wlb, fcWtb);
    cvt_strided<<<(NNODES*32 + 255)/256, blk, 0, stream>>>(x, Abuf, NNODES);
    for (int r = 0; r < 3; ++r)
        hist_kernel<<<(E[r]+255)/256, blk, 0, stream>>>(dsts[r], E[r], cnt + (size_t)r*NNODES);
    scan_part <<<dim3(NBLK,3), blk, 0, stream>>>(cnt, parts, NNODES, NBLK);
    scan_write<<<dim3(NBLK,3), blk, 0, stream>>>(cnt, parts, rowp, cur, NNODES, NBLK);
    int colOff[3] = {0, E[0], E[0]+E[1]};
    for (int r = 0; r < 3; ++r)
        scatter_kernel<<<(E[r]+255)/256, blk, 0, stream>>>(srcs[r], dsts[r], E[r],
                                                           cur + (size_t)r*NNODES, colb + colOff[r]);

    // ---- layer 0 ----
    gemm_k<3><<<dim3(1, MB), blk, 0, stream>>>(Ax, AW, 128, wlb, el, nullptr, 32, 24,
                                               NNODES, nullptr, nullptr, nullptr, nullptr, nullptr);
    for (int r = 0; r < 3; ++r)
        agg_kernel<<<WAVEBLKS, blk, 0, stream>>>(rowp + (size_t)r*(NNODES+1), colb + colOff[r],
                                                 el, r*8, Ax, Abuf + r*512, NNODES);
    gemm_k<4><<<dim3(1, MB), blk, 0, stream>>>(Abuf, AW, AW, Btb, nullptr, hmb, 128, 128,
                                               NNODES, biasf, nullptr, nullptr, nullptr, nullptr);
    gemm_k<2><<<dim3(1, MB), blk, 0, stream>>>(hmb, 128, 128, fcWtb, nullptr, Ax, AW, 128,
                                               NNODES, fcb, gamma, beta, bmean, bvar);

    // ---- layer 1 ----
    gemm_k<3><<<dim3(1, MB), blk, 0, stream>>>(Ax, AW, 128, wlb + 16384, el, nullptr, 32, 24,
                                               NNODES, nullptr, nullptr, nullptr, nullptr, nullptr);
    for (int r = 0; r < 3; ++r)
        agg_kernel<<<WAVEBLKS, blk, 0, stream>>>(rowp + (size_t)r*(NNODES+1), colb + colOff[r],
                                                 el, r*8, Ax, Abuf + r*512, NNODES);
    gemm_k<1><<<dim3(1, MB), blk, 0, stream>>>(Abuf, AW, AW, Btb + (size_t)128*AW, out, nullptr, 128, 128,
                                               NNODES, biasf + 128, nullptr, nullptr, nullptr, nullptr);
}